// Round 9
// baseline (160.674 us; speedup 1.0000x reference)
//
#include <hip/hip_runtime.h>
#include <math.h>

namespace {

typedef float f32x4 __attribute__((ext_vector_type(4)));

constexpr int kPts  = 2 * 256 * 256;   // 131072 points
constexpr int kHid  = 64;
constexpr int kPath = 384;

// ws float-index layout: ru[kPts*4] | V[384] | flag | pad | table[1024*16]
constexpr size_t kVOff    = (size_t)kPts * 4;          // 524288
constexpr size_t kFlagOff = kVOff + kPath;             // 524672
constexpr size_t kTabOff  = kVOff + 512;               // 524800 (64B-aligned)
constexpr size_t kNeedBytes = (kTabOff + 1024 * 16) * sizeof(float);

// SH / norm constants
constexpr float kY0   = 0.28209479177387814f;
constexpr float kC1   = 0.4886025119029199f;
constexpr float kC2A  = 1.0925484305920792f;
constexpr float kC2B  = 0.31539156525252005f;
constexpr float kC2C  = 0.5462742152960396f;
constexpr float kS4pi = 3.5449077018110318f;
constexpr float kSq3  = 1.7320508075688772f;
constexpr float kN00  = kS4pi / 64.f;
constexpr float kN01  = kSq3 * kS4pi / 64.f;
constexpr float kN10  = kS4pi / 90.50966799187809f;
constexpr float kN11  = kSq3 * kS4pi / 90.50966799187809f;

// ---------------- prep: ru + V + flag + per-row coefficient table ----------------
__global__ __launch_bounds__(256)
void prep_kernel(const float* __restrict__ dm,
                 const float* __restrict__ W1,
                 const float* __restrict__ b1,
                 const float* __restrict__ W2,
                 const float* __restrict__ b2,
                 const float* __restrict__ Q00,
                 const float* __restrict__ Q01,
                 const float* __restrict__ Q10,
                 const float* __restrict__ Q11,
                 f32x4* __restrict__ ru,
                 float* __restrict__ V,
                 unsigned* __restrict__ flag,
                 float* __restrict__ table)
{
    const int pt = blockIdx.x * 256 + threadIdx.x;
    {
        float dx = dm[3 * pt], dy = dm[3 * pt + 1], dz = dm[3 * pt + 2];
        float r  = sqrtf(dx * dx + dy * dy + dz * dz);
        float inv = 1.f / fmaxf(r, 1e-12f);
        f32x4 q; q.x = r; q.y = dx * inv; q.z = dy * inv; q.w = dz * inv;
        ru[pt] = q;
    }
    if (blockIdx.x != 0) return;

    for (int p = threadIdx.x; p < kPath; p += 256) {
        float acc = 0.f;
        for (int i = 0; i < kHid; ++i)
            acc += fmaxf(W1[i], 0.f) * W2[i * kPath + p];
        V[p] = acc;
    }
    if (threadIdx.x == 0) {
        unsigned f = 1u;
        for (int i = 0; i < kHid; ++i)
            if (b1[i] != 0.f) f = 0u;
        *flag = f;
    }
    __syncthreads();

    for (int row = threadIdx.x; row < 1024; row += 256) {
        const int rA = row >> 5, rB = row & 31;
        float p0=0, a0=0, a1=0, a2=0, b0=0, b1v=0, b2c=0, b3=0, b4=0;
        float vx=0, cx=0, vy=0, cy=0, vz=0, cz=0;
        if (rA < 8) {
            const int u = rA;
            if (rB < 8) {
                const int uv = u * 8 + rB;
                p0 = kN00 * Q00[0] * kY0;
                vx = V[uv]; cx = b2[uv];
            } else {
                const int v = (rB - 8) / 3, jc = (rB - 8) % 3, uv = u * 8 + v;
                a0 = kN01 * kC1 * Q01[jc * 3 + 0];
                a1 = kN01 * kC1 * Q01[jc * 3 + 1];
                a2 = kN01 * kC1 * Q01[jc * 3 + 2];
                vy = V[64 + uv]; cy = b2[64 + uv];
            }
        } else {
            const int t = rA - 8, u = t / 3, ir = t % 3;
            if (rB < 8) {
                const int uv = u * 8 + rB;
                a0 = kN10 * kC1 * Q10[ir * 3 + 0];
                a1 = kN10 * kC1 * Q10[ir * 3 + 1];
                a2 = kN10 * kC1 * Q10[ir * 3 + 2];
                vy = V[128 + uv]; cy = b2[128 + uv];
            } else {
                const int v = (rB - 8) / 3, jc = (rB - 8) % 3;
                const int e = ir * 3 + jc, uv = u * 8 + v;
                const float* q = Q11 + e * 9;
                p0 = kN11 * kY0 * q[0];
                vx = V[192 + 3 * uv]; cx = b2[192 + 3 * uv];
                a0 = kN11 * kC1 * q[1];
                a1 = kN11 * kC1 * q[2];
                a2 = kN11 * kC1 * q[3];
                vy = V[193 + 3 * uv]; cy = b2[193 + 3 * uv];
                b0  = kN11 * kC2A * q[4];
                b1v = kN11 * kC2A * q[5];
                b2c = kN11 * kC2B * q[6];
                b3  = kN11 * kC2A * q[7];
                b4  = kN11 * kC2C * q[8];
                vz = V[194 + 3 * uv]; cz = b2[194 + 3 * uv];
            }
        }
        float* T = table + row * 16;
        T[0]=p0;  T[1]=a0;  T[2]=a1;  T[3]=a2;  T[4]=b0;
        T[5]=b1v; T[6]=b2c; T[7]=b3;  T[8]=b4;
        T[9]=vx;  T[10]=cx; T[11]=vy; T[12]=cy; T[13]=vz; T[14]=cz;
        T[15]=0.f;
    }
}

// ---------------- sweep: pure linear store front over the whole output ----------------
// element index e (f32x4 units): plane = e>>15, pt4 = e&32767.
// Chip-wide, concurrent stores form one contiguous window -> fill-like pattern.
__global__ __launch_bounds__(256)
void sweep_kernel(const f32x4* __restrict__ ru,
                  const float* __restrict__ table,
                  const unsigned* __restrict__ flag,
                  float* __restrict__ out)
{
    if (*flag == 0u) return;   // general path handled by predicated mono
    f32x4* __restrict__ o4 = reinterpret_cast<f32x4*>(out);
    size_t e = (size_t)blockIdx.x * 256 + threadIdx.x;

#pragma unroll 1
    for (int it = 0; it < 16; ++it, e += 8192 * 256) {
        int plane = (int)(e >> 15);
        plane = __builtin_amdgcn_readfirstlane(plane);   // wave-uniform -> SGPR
        const int pt4 = (int)(e & 32767);

        const float* __restrict__ C = table + plane * 16;
        const float p0 = C[0];
        const float a0 = C[1], a1 = C[2], a2 = C[3];
        const float b0 = C[4], b1v = C[5], b2c = C[6], b3 = C[7], b4 = C[8];
        const float vx = C[9], cx = C[10], vy = C[11], cy = C[12], vz = C[13], cz = C[14];

        const f32x4* __restrict__ rp = ru + (size_t)pt4 * 4;
        f32x4 q0 = rp[0], q1 = rp[1], q2 = rp[2], q3 = rp[3];
        float R[4] = { q0.x, q1.x, q2.x, q3.x };
        float X[4] = { q0.y, q1.y, q2.y, q3.y };
        float Y[4] = { q0.z, q1.z, q2.z, q3.z };
        float Z[4] = { q0.w, q1.w, q2.w, q3.w };

        f32x4 o;
#pragma unroll
        for (int k = 0; k < 4; ++k) {
            float wx = fmaf(R[k], vx, cx);
            float wy = fmaf(R[k], vy, cy);
            float wz = fmaf(R[k], vz, cz);
            float lin = fmaf(a2, X[k], fmaf(a1, Z[k], a0 * Y[k]));
            float zz  = fmaf(3.f * Z[k], Z[k], -1.f);
            float quad = fmaf(b0, X[k] * Y[k],
                         fmaf(b1v, Y[k] * Z[k],
                         fmaf(b2c, zz,
                         fmaf(b3, X[k] * Z[k],
                              b4 * fmaf(X[k], X[k], -(Y[k] * Y[k]))))));
            o[k] = fmaf(p0, wx, fmaf(lin, wy, quad * wz));
        }
        o4[e] = o;
    }
}

// ---------------- general-path monolith (predicated or standalone) ----------------
template <bool PRED>
__global__ __launch_bounds__(256)
void mono_kernel(const float* __restrict__ dm,
                 const float* __restrict__ W1,
                 const float* __restrict__ b1,
                 const float* __restrict__ W2,
                 const float* __restrict__ b2,
                 const float* __restrict__ Q00,
                 const float* __restrict__ Q01,
                 const float* __restrict__ Q10,
                 const float* __restrict__ Q11,
                 const unsigned* __restrict__ flag,
                 float* __restrict__ out)
{
    if constexpr (PRED) { if (*flag != 0u) return; }
    const int g   = blockIdx.x * blockDim.x + threadIdx.x;  // 4 points
    const int uv0 = blockIdx.y * 8;

    const f32x4* dmv = reinterpret_cast<const f32x4*>(dm) + 3 * (size_t)g;
    f32x4 f0 = dmv[0], f1 = dmv[1], f2 = dmv[2];
    float px[4] = { f0.x, f0.w, f1.z, f2.y };
    float py[4] = { f0.y, f1.x, f1.w, f2.z };
    float pz[4] = { f0.z, f1.y, f2.x, f2.w };

    float r[4], ux[4], uy[4], uz[4];
#pragma unroll
    for (int p = 0; p < 4; ++p) {
        r[p] = sqrtf(px[p]*px[p] + py[p]*py[p] + pz[p]*pz[p]);
        float inv = 1.0f / fmaxf(r[p], 1e-12f);
        ux[p] = px[p]*inv; uy[p] = py[p]*inv; uz[p] = pz[p]*inv;
    }
    float Y10[4], Y11v[4], Y12[4], Y2[5][4];
#pragma unroll
    for (int p = 0; p < 4; ++p) {
        Y10[p] = kC1 * uy[p]; Y11v[p] = kC1 * uz[p]; Y12[p] = kC1 * ux[p];
        Y2[0][p] = kC2A * ux[p] * uy[p];
        Y2[1][p] = kC2A * uy[p] * uz[p];
        Y2[2][p] = kC2B * (3.f * uz[p] * uz[p] - 1.f);
        Y2[3][p] = kC2A * ux[p] * uz[p];
        Y2[4][p] = kC2C * (ux[p]*ux[p] - uy[p]*uy[p]);
    }
    const float s00 = kN00 * Q00[0] * kY0;
    float G0[9];
#pragma unroll
    for (int e = 0; e < 9; ++e) G0[e] = kN11 * Q11[e*9] * kY0;
    float g01[3][4], g10[3][4], G1[9][4], G2[9][4];
#pragma unroll
    for (int jc = 0; jc < 3; ++jc)
#pragma unroll
        for (int p = 0; p < 4; ++p)
            g01[jc][p] = kN01 * (Q01[jc*3]*Y10[p] + Q01[jc*3+1]*Y11v[p] + Q01[jc*3+2]*Y12[p]);
#pragma unroll
    for (int ir = 0; ir < 3; ++ir)
#pragma unroll
        for (int p = 0; p < 4; ++p)
            g10[ir][p] = kN10 * (Q10[ir*3]*Y10[p] + Q10[ir*3+1]*Y11v[p] + Q10[ir*3+2]*Y12[p]);
#pragma unroll
    for (int e = 0; e < 9; ++e) {
        const float* q = Q11 + e * 9;
#pragma unroll
        for (int p = 0; p < 4; ++p) {
            G1[e][p] = kN11 * (q[1]*Y10[p] + q[2]*Y11v[p] + q[3]*Y12[p]);
            G2[e][p] = kN11 * (q[4]*Y2[0][p] + q[5]*Y2[1][p] + q[6]*Y2[2][p] +
                               q[7]*Y2[3][p] + q[8]*Y2[4][p]);
        }
    }
    float* __restrict__ obase = out + 4 * (size_t)g;
    auto stf = [&](int row, const float* v4) {
        f32x4 q; q.x=v4[0]; q.y=v4[1]; q.z=v4[2]; q.w=v4[3];
        *reinterpret_cast<f32x4*>(obase + (size_t)row * kPts) = q;
    };
#pragma unroll 1
    for (int t = 0; t < 8; ++t) {
        const int uv = uv0 + t;
        float a00[4], a01v[4], a10v[4], a110[4], a111[4], a112[4];
#pragma unroll
        for (int p = 0; p < 4; ++p) {
            a00[p]=b2[uv]; a01v[p]=b2[64+uv]; a10v[p]=b2[128+uv];
            a110[p]=b2[192+3*uv]; a111[p]=b2[193+3*uv]; a112[p]=b2[194+3*uv];
        }
#pragma unroll 1
        for (int i = 0; i < kHid; ++i) {
            float w1i = W1[i], b1i = b1[i];
            const float* row = W2 + (size_t)i * kPath;
            float c00=row[uv], c01=row[64+uv], c10=row[128+uv];
            float c50=row[192+3*uv], c51=row[193+3*uv], c52=row[194+3*uv];
#pragma unroll
            for (int p = 0; p < 4; ++p) {
                float hi = fmaxf(fmaf(r[p], w1i, b1i), 0.f);
                a00[p]=fmaf(hi,c00,a00[p]); a01v[p]=fmaf(hi,c01,a01v[p]);
                a10v[p]=fmaf(hi,c10,a10v[p]); a110[p]=fmaf(hi,c50,a110[p]);
                a111[p]=fmaf(hi,c51,a111[p]); a112[p]=fmaf(hi,c52,a112[p]);
            }
        }
        const int u = uv >> 3, v = uv & 7;
        const int rowu = u * 32;
        float tmp[4];
#pragma unroll
        for (int p = 0; p < 4; ++p) tmp[p] = s00 * a00[p];
        stf(rowu + v, tmp);
#pragma unroll
        for (int jc = 0; jc < 3; ++jc) {
#pragma unroll
            for (int p = 0; p < 4; ++p) tmp[p] = g01[jc][p] * a01v[p];
            stf(rowu + 8 + v*3 + jc, tmp);
        }
#pragma unroll
        for (int ir = 0; ir < 3; ++ir) {
            const int rowb = (8 + u*3 + ir) * 32;
#pragma unroll
            for (int p = 0; p < 4; ++p) tmp[p] = g10[ir][p] * a10v[p];
            stf(rowb + v, tmp);
#pragma unroll
            for (int jc = 0; jc < 3; ++jc) {
                const int e = ir*3 + jc;
#pragma unroll
                for (int p = 0; p < 4; ++p)
                    tmp[p] = fmaf(G0[e], a110[p], fmaf(G1[e][p], a111[p], G2[e][p]*a112[p]));
                stf(rowb + 8 + v*3 + jc, tmp);
            }
        }
    }
}

} // namespace

extern "C" void kernel_launch(void* const* d_in, const int* in_sizes, int n_in,
                              void* d_out, int out_size, void* d_ws, size_t ws_size,
                              hipStream_t stream)
{
    const float* dm  = (const float*)d_in[0];
    const float* W1  = (const float*)d_in[1];
    const float* b1  = (const float*)d_in[2];
    const float* W2  = (const float*)d_in[3];
    const float* b2  = (const float*)d_in[4];
    const float* Q00 = (const float*)d_in[5];
    const float* Q01 = (const float*)d_in[6];
    const float* Q10 = (const float*)d_in[7];
    const float* Q11 = (const float*)d_in[8];
    float* out = (float*)d_out;

    if (ws_size >= kNeedBytes) {
        float*    ws    = (float*)d_ws;
        f32x4*    ru    = (f32x4*)ws;
        float*    V     = ws + kVOff;
        unsigned* flag  = (unsigned*)(ws + kFlagOff);
        float*    table = ws + kTabOff;
        prep_kernel<<<kPts / 256, 256, 0, stream>>>(
            dm, W1, b1, W2, b2, Q00, Q01, Q10, Q11, ru, V, flag, table);
        mono_kernel<true><<<dim3(kPts / 4 / 256, 8), 256, 0, stream>>>(
            dm, W1, b1, W2, b2, Q00, Q01, Q10, Q11, flag, out);
        sweep_kernel<<<8192, 256, 0, stream>>>(ru, table, flag, out);
    } else {
        mono_kernel<false><<<dim3(kPts / 4 / 256, 8), 256, 0, stream>>>(
            dm, W1, b1, W2, b2, Q00, Q01, Q10, Q11, nullptr, out);
    }
}